// Round 1
// baseline (282.214 us; speedup 1.0000x reference)
//
#include <hip/hip_runtime.h>
#include <hip/hip_bf16.h>

#define BATCH 8
#define TLEN 2048
#define XT_ROWS (TLEN + 64)            // 64 zero-pad rows + 2048
#define GT_BYTES (2048*1024*2)         // Gt[2048][32][32] bf16 = 4 MiB
#define XT_BYTES (BATCH*XT_ROWS*32*2)  // 1,081,344 B
#define PART_OFF ((GT_BYTES + XT_BYTES + 255) & ~255)
#define JOBS_PER_B 528
#define NJOBS (BATCH*JOBS_PER_B)       // 4224

using short8 = __attribute__((ext_vector_type(8))) short;
using f32x4  = __attribute__((ext_vector_type(4))) float;

// ---------------- K1: SIREN kernel net -> Gt[d][o][i] (bf16), d = t - tau ----------------
// Gt[d][o][i] = kernel[o][i][2048-d] = w3[o*32+i,:] @ sin(w2 @ sin(w1*p[2048-d]+b1) + b2) + b3
__global__ void gen_kernel(const float* __restrict__ pos, const float* __restrict__ w1,
                           const float* __restrict__ b1, const float* __restrict__ w2,
                           const float* __restrict__ b2, const float* __restrict__ w3,
                           const float* __restrict__ b3, __hip_bfloat16* __restrict__ Gt) {
    __shared__ float t1s[8][33];
    __shared__ float h2s[8][33];
    int tid = threadIdx.x;
    int d0 = blockIdx.x * 8;
    int dl = tid >> 5, jj = tid & 31;      // 8 d's x 32 neurons
    {
        int d = d0 + dl;
        float p = pos[2048 - d];           // kernel position index L-1-d
        t1s[dl][jj] = sinf(w1[jj] * p + b1[jj]);
    }
    __syncthreads();
    {
        float a = b2[jj];
        #pragma unroll
        for (int k = 0; k < 32; ++k) a += w2[jj*32 + k] * t1s[dl][k];
        h2s[dl][jj] = sinf(a);
    }
    __syncthreads();
    for (int r = 0; r < 32; ++r) {
        int idx = r*256 + tid;
        int dl2 = idx >> 10, oi = idx & 1023;
        float a = b3[oi];
        #pragma unroll
        for (int k = 0; k < 32; ++k) a += w3[oi*32 + k] * h2s[dl2][k];
        Gt[(size_t)(d0 + dl2)*1024 + oi] = __float2bfloat16(a);
    }
}

// ---------------- K2: x (B,CIN,T) f32 -> xT[b][64+tau][i] bf16, 64 zero rows ----------------
__global__ void transpose_x(const float* __restrict__ x, __hip_bfloat16* __restrict__ xT) {
    __shared__ float tile[32][65];
    int tid = threadIdx.x;
    int b = blockIdx.x >> 5;
    int c = blockIdx.x & 31;
    int t0 = c * 64;
    #pragma unroll
    for (int r = 0; r < 8; ++r) {
        int i  = r*4 + (tid >> 6);
        int tl = tid & 63;
        tile[i][tl] = x[((size_t)(b*32 + i))*TLEN + t0 + tl];
    }
    __syncthreads();
    #pragma unroll
    for (int r = 0; r < 8; ++r) {
        int idx = r*256 + tid;
        int tl = idx >> 5, i = idx & 31;
        xT[((size_t)(b*XT_ROWS + 64 + t0 + tl))*32 + i] = __float2bfloat16(tile[i][tl]);
    }
    if (c == 0) {  // zero the causal pad rows
        for (int idx = tid; idx < 64*32; idx += 256)
            xT[(size_t)b*XT_ROWS*32 + idx] = __float2bfloat16(0.0f);
    }
}

// ---------------- K3: MFMA conv. wave job = (b, t-block j of 64, d-segment s of 64) --------
// out-tile 64t x 32o per wave; A[m=t][k=i] = xT[b][64+t0+m-d][i]; B[k=i][n=o] = Gt[d][o][i]
__global__ __launch_bounds__(256) void conv_mfma(const __hip_bfloat16* __restrict__ GtB,
                                                 const __hip_bfloat16* __restrict__ xTB,
                                                 float* __restrict__ partial) {
    int tid  = threadIdx.x;
    int wid  = blockIdx.x * 4 + (tid >> 6);
    int lane = tid & 63;
    int b    = wid / JOBS_PER_B;
    int rem  = wid - b * JOBS_PER_B;
    int j = (int)((sqrtf(8.0f*rem + 1.0f) - 1.0f) * 0.5f);
    while ((j+1)*(j+2)/2 <= rem) ++j;
    while (j*(j+1)/2 > rem) --j;
    int s = rem - j*(j+1)/2;

    int l15 = lane & 15, l4 = lane >> 4;
    const short8* xs = (const short8*)xTB;   // 8-elem (16B) units
    const short8* gs = (const short8*)GtB;
    // A frag: lane reads xT row (64 + 64j + l15 + 16mt - d), i-offset l4*8 (16B)
    int abase = (b*XT_ROWS + 64 + 64*j + l15)*4 + l4;   // row stride = 4 short8
    int gbase = l15*4 + l4;                              // Gt[d][o=l15][i=l4*8]

    f32x4 acc[4][2];
    const f32x4 zero = {0.f, 0.f, 0.f, 0.f};
    #pragma unroll
    for (int mt = 0; mt < 4; ++mt) { acc[mt][0] = zero; acc[mt][1] = zero; }

    int dlo = 64*s, dhi = dlo + 64;
    for (int d = dlo; d < dhi; ++d) {
        short8 bv0 = gs[d*128 + gbase];        // o in [0,16)
        short8 bv1 = gs[d*128 + gbase + 64];   // o in [16,32)
        int a0 = abase - d*4;
        #pragma unroll
        for (int mt = 0; mt < 4; ++mt) {
            short8 av = xs[a0 + mt*64];        // 16 rows per mt
            acc[mt][0] = __builtin_amdgcn_mfma_f32_16x16x32_bf16(av, bv0, acc[mt][0], 0, 0, 0);
            acc[mt][1] = __builtin_amdgcn_mfma_f32_16x16x32_bf16(av, bv1, acc[mt][1], 0, 0, 0);
        }
    }
    // partial[wid][o][t_local]  (o-major so the reducer reads coalesced)
    float* pw = partial + (size_t)wid * 2048;
    #pragma unroll
    for (int no = 0; no < 2; ++no)
        #pragma unroll
        for (int mt = 0; mt < 4; ++mt) {
            int addr = (16*no + l15)*64 + 16*mt + l4*4;   // D: n=lane&15, m=(lane>>4)*4+r
            *reinterpret_cast<f32x4*>(pw + addr) = acc[mt][no];
        }
}

// ---------------- K4: sum the j+1 segments of each (b,j) tile, add bias ----------------
__global__ void reduce_out(const float* __restrict__ partial, const float* __restrict__ bias,
                           float* __restrict__ out) {
    int tid = threadIdx.x;
    int b = blockIdx.x >> 5;
    int j = blockIdx.x & 31;
    int base = b*JOBS_PER_B + j*(j+1)/2;
    int cnt  = j + 1;
    #pragma unroll
    for (int r = 0; r < 8; ++r) {
        int e  = r*256 + tid;
        int o  = e >> 6, tl = e & 63;
        float ssum = bias[o];
        for (int sg = 0; sg < cnt; ++sg)
            ssum += partial[((size_t)(base + sg))*2048 + o*64 + tl];
        out[((size_t)(b*32 + o))*TLEN + 64*j + tl] = ssum;
    }
}

extern "C" void kernel_launch(void* const* d_in, const int* in_sizes, int n_in,
                              void* d_out, int out_size, void* d_ws, size_t ws_size,
                              hipStream_t stream) {
    const float* x    = (const float*)d_in[0];
    const float* pos  = (const float*)d_in[1];
    const float* w1   = (const float*)d_in[2];
    const float* b1   = (const float*)d_in[3];
    const float* w2   = (const float*)d_in[4];
    const float* b2   = (const float*)d_in[5];
    const float* w3   = (const float*)d_in[6];
    const float* b3   = (const float*)d_in[7];
    const float* bias = (const float*)d_in[8];
    float* out = (float*)d_out;

    char* ws = (char*)d_ws;
    __hip_bfloat16* Gt = (__hip_bfloat16*)ws;
    __hip_bfloat16* xT = (__hip_bfloat16*)(ws + GT_BYTES);
    float* partial     = (float*)(ws + PART_OFF);

    hipLaunchKernelGGL(gen_kernel,  dim3(256),      dim3(256), 0, stream,
                       pos, w1, b1, w2, b2, w3, b3, Gt);
    hipLaunchKernelGGL(transpose_x, dim3(256),      dim3(256), 0, stream, x, xT);
    hipLaunchKernelGGL(conv_mfma,   dim3(NJOBS/4),  dim3(256), 0, stream, Gt, xT, partial);
    hipLaunchKernelGGL(reduce_out,  dim3(256),      dim3(256), 0, stream, partial, bias, out);
}

// Round 2
// 240.525 us; speedup vs baseline: 1.1733x; 1.1733x over previous
//
#include <hip/hip_runtime.h>
#include <hip/hip_bf16.h>

#define BATCH 8
#define TLEN 2048
#define XT_ROWS (TLEN + 64)            // 64 zero-pad rows + 2048
#define GT_BYTES (2048*1024*2)         // Gt[2048][32][32] bf16 = 4 MiB
#define XT_BYTES (BATCH*XT_ROWS*32*2)  // 1,081,344 B
#define PART_OFF ((GT_BYTES + XT_BYTES + 255) & ~255)
#define JOBS_PER_B 528
#define NJOBS (BATCH*JOBS_PER_B)       // 4224

using short8 = __attribute__((ext_vector_type(8))) short;
using f32x4  = __attribute__((ext_vector_type(4))) float;

// ---------------- K1: SIREN kernel net -> Gt[d][o][i] (bf16), d = t - tau ----------------
__global__ void gen_kernel(const float* __restrict__ pos, const float* __restrict__ w1,
                           const float* __restrict__ b1, const float* __restrict__ w2,
                           const float* __restrict__ b2, const float* __restrict__ w3,
                           const float* __restrict__ b3, __hip_bfloat16* __restrict__ Gt) {
    __shared__ float t1s[8][33];
    __shared__ float h2s[8][33];
    int tid = threadIdx.x;
    int d0 = blockIdx.x * 8;
    int dl = tid >> 5, jj = tid & 31;
    {
        int d = d0 + dl;
        float p = pos[2048 - d];
        t1s[dl][jj] = sinf(w1[jj] * p + b1[jj]);
    }
    __syncthreads();
    {
        float a = b2[jj];
        #pragma unroll
        for (int k = 0; k < 32; ++k) a += w2[jj*32 + k] * t1s[dl][k];
        h2s[dl][jj] = sinf(a);
    }
    __syncthreads();
    for (int r = 0; r < 32; ++r) {
        int idx = r*256 + tid;
        int dl2 = idx >> 10, oi = idx & 1023;
        float a = b3[oi];
        #pragma unroll
        for (int k = 0; k < 32; ++k) a += w3[oi*32 + k] * h2s[dl2][k];
        Gt[(size_t)(d0 + dl2)*1024 + oi] = __float2bfloat16(a);
    }
}

// ---------------- K2: x (B,CIN,T) f32 -> xT[b][64+tau][i] bf16, 64 zero rows ----------------
__global__ void transpose_x(const float* __restrict__ x, __hip_bfloat16* __restrict__ xT) {
    __shared__ float tile[32][65];
    int tid = threadIdx.x;
    int b = blockIdx.x >> 5;
    int c = blockIdx.x & 31;
    int t0 = c * 64;
    #pragma unroll
    for (int r = 0; r < 8; ++r) {
        int i  = r*4 + (tid >> 6);
        int tl = tid & 63;
        tile[i][tl] = x[((size_t)(b*32 + i))*TLEN + t0 + tl];
    }
    __syncthreads();
    #pragma unroll
    for (int r = 0; r < 8; ++r) {
        int idx = r*256 + tid;
        int tl = idx >> 5, i = idx & 31;
        xT[((size_t)(b*XT_ROWS + 64 + t0 + tl))*32 + i] = __float2bfloat16(tile[i][tl]);
    }
    if (c == 0) {
        for (int idx = tid; idx < 64*32; idx += 256)
            xT[(size_t)b*XT_ROWS*32 + idx] = __float2bfloat16(0.0f);
    }
}

// ---------------- K3: MFMA conv, register-double-buffered (prefetch d+1 while MFMA d) ------
#define MFMA8(A0,A1,A2,A3,B0,B1)                                                  \
    acc[0][0] = __builtin_amdgcn_mfma_f32_16x16x32_bf16(A0, B0, acc[0][0], 0,0,0); \
    acc[0][1] = __builtin_amdgcn_mfma_f32_16x16x32_bf16(A0, B1, acc[0][1], 0,0,0); \
    acc[1][0] = __builtin_amdgcn_mfma_f32_16x16x32_bf16(A1, B0, acc[1][0], 0,0,0); \
    acc[1][1] = __builtin_amdgcn_mfma_f32_16x16x32_bf16(A1, B1, acc[1][1], 0,0,0); \
    acc[2][0] = __builtin_amdgcn_mfma_f32_16x16x32_bf16(A2, B0, acc[2][0], 0,0,0); \
    acc[2][1] = __builtin_amdgcn_mfma_f32_16x16x32_bf16(A2, B1, acc[2][1], 0,0,0); \
    acc[3][0] = __builtin_amdgcn_mfma_f32_16x16x32_bf16(A3, B0, acc[3][0], 0,0,0); \
    acc[3][1] = __builtin_amdgcn_mfma_f32_16x16x32_bf16(A3, B1, acc[3][1], 0,0,0);

__global__ __launch_bounds__(256) void conv_mfma(const __hip_bfloat16* __restrict__ GtB,
                                                 const __hip_bfloat16* __restrict__ xTB,
                                                 float* __restrict__ partial) {
    int tid   = threadIdx.x;
    int lane  = tid & 63;
    int wslot = blockIdx.x * 4 + (tid >> 6);   // 0..4095
    int l15 = lane & 15, l4 = lane >> 4;
    const short8* xs = (const short8*)xTB;
    const short8* gs = (const short8*)GtB;

    // job list: own slot, plus one of the 128 leftover jobs scattered via *33 (bijective mod 4096)
    int e = (wslot * 993) & 4095;              // 993 = 33^-1 mod 4096
    int njq = (e < 128) ? 2 : 1;

    for (int q = 0; q < njq; ++q) {
        int wid = (q == 0) ? wslot : (4096 + e);
        int b   = wid / JOBS_PER_B;
        int rem = wid - b * JOBS_PER_B;
        int j = (int)((sqrtf(8.0f*rem + 1.0f) - 1.0f) * 0.5f);
        while ((j+1)*(j+2)/2 <= rem) ++j;
        while (j*(j+1)/2 > rem) --j;
        int s = rem - j*(j+1)/2;
        int dlo = 64*s;

        int abase = (b*XT_ROWS + 64 + 64*j + l15)*4 + l4;  // row stride = 4 short8
        int gbase = l15*4 + l4;
        const short8* gp = gs + (size_t)dlo*128 + gbase;
        const short8* ap = xs + (abase - dlo*4);

        f32x4 acc[4][2];
        const f32x4 zero = {0.f, 0.f, 0.f, 0.f};
        #pragma unroll
        for (int mt = 0; mt < 4; ++mt) { acc[mt][0] = zero; acc[mt][1] = zero; }

        // prologue: set-x <- d = dlo
        short8 xb0 = gp[0], xb1 = gp[64];
        short8 xa0 = ap[0], xa1 = ap[64], xa2 = ap[128], xa3 = ap[192];
        short8 yb0, yb1, ya0, ya1, ya2, ya3;

        for (int it = 0; it < 31; ++it) {       // pairs (2k, 2k+1), k=0..30 -> d up to 62 loaded
            gp += 128; ap -= 4;                 // d = 2k+1
            yb0 = gp[0]; yb1 = gp[64];
            ya0 = ap[0]; ya1 = ap[64]; ya2 = ap[128]; ya3 = ap[192];
            MFMA8(xa0, xa1, xa2, xa3, xb0, xb1) // d = 2k
            gp += 128; ap -= 4;                 // d = 2k+2
            xb0 = gp[0]; xb1 = gp[64];
            xa0 = ap[0]; xa1 = ap[64]; xa2 = ap[128]; xa3 = ap[192];
            MFMA8(ya0, ya1, ya2, ya3, yb0, yb1) // d = 2k+1
        }
        gp += 128; ap -= 4;                     // d = 63
        yb0 = gp[0]; yb1 = gp[64];
        ya0 = ap[0]; ya1 = ap[64]; ya2 = ap[128]; ya3 = ap[192];
        MFMA8(xa0, xa1, xa2, xa3, xb0, xb1)     // d = 62
        MFMA8(ya0, ya1, ya2, ya3, yb0, yb1)     // d = 63

        float* pw = partial + (size_t)wid * 2048;
        #pragma unroll
        for (int no = 0; no < 2; ++no)
            #pragma unroll
            for (int mt = 0; mt < 4; ++mt) {
                int addr = (16*no + l15)*64 + 16*mt + l4*4;
                *reinterpret_cast<f32x4*>(pw + addr) = acc[mt][no];
            }
    }
}

// ---------------- K4: per-element reduction, full occupancy, 4 independent chains ---------
__global__ void reduce_out(const float* __restrict__ partial, const float* __restrict__ bias,
                           float* __restrict__ out) {
    int gid = blockIdx.x * 256 + threadIdx.x;  // 524288 elems
    int tl = gid & 63;
    int j  = (gid >> 6) & 31;
    int o  = (gid >> 11) & 31;
    int b  = gid >> 16;
    const float* p = partial + (size_t)(b*JOBS_PER_B + j*(j+1)/2)*2048 + o*64 + tl;
    int cnt = j + 1;
    float s0 = 0.f, s1 = 0.f, s2 = 0.f, s3 = 0.f;
    int sg = 0;
    for (; sg + 4 <= cnt; sg += 4) {
        s0 += p[(size_t)sg*2048];
        s1 += p[(size_t)(sg+1)*2048];
        s2 += p[(size_t)(sg+2)*2048];
        s3 += p[(size_t)(sg+3)*2048];
    }
    for (; sg < cnt; ++sg) s0 += p[(size_t)sg*2048];
    out[((size_t)(b*32 + o))*TLEN + 64*j + tl] = bias[o] + ((s0 + s1) + (s2 + s3));
}

extern "C" void kernel_launch(void* const* d_in, const int* in_sizes, int n_in,
                              void* d_out, int out_size, void* d_ws, size_t ws_size,
                              hipStream_t stream) {
    const float* x    = (const float*)d_in[0];
    const float* pos  = (const float*)d_in[1];
    const float* w1   = (const float*)d_in[2];
    const float* b1   = (const float*)d_in[3];
    const float* w2   = (const float*)d_in[4];
    const float* b2   = (const float*)d_in[5];
    const float* w3   = (const float*)d_in[6];
    const float* b3   = (const float*)d_in[7];
    const float* bias = (const float*)d_in[8];
    float* out = (float*)d_out;

    char* ws = (char*)d_ws;
    __hip_bfloat16* Gt = (__hip_bfloat16*)ws;
    __hip_bfloat16* xT = (__hip_bfloat16*)(ws + GT_BYTES);
    float* partial     = (float*)(ws + PART_OFF);

    hipLaunchKernelGGL(gen_kernel,  dim3(256),  dim3(256), 0, stream,
                       pos, w1, b1, w2, b2, w3, b3, Gt);
    hipLaunchKernelGGL(transpose_x, dim3(256),  dim3(256), 0, stream, x, xT);
    hipLaunchKernelGGL(conv_mfma,   dim3(1024), dim3(256), 0, stream, Gt, xT, partial);
    hipLaunchKernelGGL(reduce_out,  dim3(2048), dim3(256), 0, stream, partial, bias, out);
}

// Round 4
// 163.606 us; speedup vs baseline: 1.7250x; 1.4701x over previous
//
#include <hip/hip_runtime.h>
#include <hip/hip_bf16.h>

#define BATCH 8
#define TLEN 2048
#define PADR 256
#define XT_ROWS (TLEN + PADR + 64)     // 2368 rows (64 slack rows at tail)
#define GT_BYTES (2048*1024*2)         // Gt[2048][32][32] bf16 = 4 MiB
#define XT_BYTES (BATCH*XT_ROWS*32*2)
#define PART_OFF ((GT_BYTES + XT_BYTES + 255) & ~255)
#define JOBS_PER_B 144                 // sum over J=0..7 of 4*(J+1)
#define NJOBS (BATCH*JOBS_PER_B)       // 1152

using short8 = __attribute__((ext_vector_type(8))) short;
using f32x4  = __attribute__((ext_vector_type(4))) float;

// ---------------- K1: SIREN kernel net -> Gt[d][o][i] (bf16), d = t - tau ----------------
__global__ void gen_kernel(const float* __restrict__ pos, const float* __restrict__ w1,
                           const float* __restrict__ b1, const float* __restrict__ w2,
                           const float* __restrict__ b2, const float* __restrict__ w3,
                           const float* __restrict__ b3, __hip_bfloat16* __restrict__ Gt) {
    __shared__ float t1s[8][33];
    __shared__ float h2s[8][33];
    int tid = threadIdx.x;
    int d0 = blockIdx.x * 8;
    int dl = tid >> 5, jj = tid & 31;
    {
        int d = d0 + dl;
        float p = pos[2048 - d];
        t1s[dl][jj] = sinf(w1[jj] * p + b1[jj]);
    }
    __syncthreads();
    {
        float a = b2[jj];
        #pragma unroll
        for (int k = 0; k < 32; ++k) a += w2[jj*32 + k] * t1s[dl][k];
        h2s[dl][jj] = sinf(a);
    }
    __syncthreads();
    for (int r = 0; r < 32; ++r) {
        int idx = r*256 + tid;
        int dl2 = idx >> 10, oi = idx & 1023;
        float a = b3[oi];
        #pragma unroll
        for (int k = 0; k < 32; ++k) a += w3[oi*32 + k] * h2s[dl2][k];
        Gt[(size_t)(d0 + dl2)*1024 + oi] = __float2bfloat16(a);
    }
}

// ---------------- K2: x (B,CIN,T) f32 -> xT[b][PADR+t][i] bf16, PADR zero rows ------------
__global__ void transpose_x(const float* __restrict__ x, __hip_bfloat16* __restrict__ xT) {
    __shared__ float tile[32][65];
    int tid = threadIdx.x;
    int b = blockIdx.x >> 5;
    int c = blockIdx.x & 31;
    int t0 = c * 64;
    #pragma unroll
    for (int r = 0; r < 8; ++r) {
        int i  = r*4 + (tid >> 6);
        int tl = tid & 63;
        tile[i][tl] = x[((size_t)(b*32 + i))*TLEN + t0 + tl];
    }
    __syncthreads();
    #pragma unroll
    for (int r = 0; r < 8; ++r) {
        int idx = r*256 + tid;
        int tl = idx >> 5, i = idx & 31;
        xT[((size_t)(b*XT_ROWS + PADR + t0 + tl))*32 + i] = __float2bfloat16(tile[i][tl]);
    }
    if (c == 0) {   // zero the causal pad rows [0, PADR)
        for (int idx = tid; idx < PADR*32; idx += 256)
            xT[(size_t)b*XT_ROWS*32 + idx] = __float2bfloat16(0.0f);
    }
    if (c == 1) {   // zero the tail slack rows
        for (int idx = tid; idx < 64*32; idx += 256)
            xT[((size_t)b*XT_ROWS + PADR + TLEN)*32 + idx] = __float2bfloat16(0.0f);
    }
}

// ---------------- K3: WG job = (b, 256-row t-block J, 64-d segment S). A in LDS. ----------
#define MFMA8(A0,A1,A2,A3,B0,B1)                                                  \
    acc[0][0] = __builtin_amdgcn_mfma_f32_16x16x32_bf16(A0, B0, acc[0][0], 0,0,0); \
    acc[0][1] = __builtin_amdgcn_mfma_f32_16x16x32_bf16(A0, B1, acc[0][1], 0,0,0); \
    acc[1][0] = __builtin_amdgcn_mfma_f32_16x16x32_bf16(A1, B0, acc[1][0], 0,0,0); \
    acc[1][1] = __builtin_amdgcn_mfma_f32_16x16x32_bf16(A1, B1, acc[1][1], 0,0,0); \
    acc[2][0] = __builtin_amdgcn_mfma_f32_16x16x32_bf16(A2, B0, acc[2][0], 0,0,0); \
    acc[2][1] = __builtin_amdgcn_mfma_f32_16x16x32_bf16(A2, B1, acc[2][1], 0,0,0); \
    acc[3][0] = __builtin_amdgcn_mfma_f32_16x16x32_bf16(A3, B0, acc[3][0], 0,0,0); \
    acc[3][1] = __builtin_amdgcn_mfma_f32_16x16x32_bf16(A3, B1, acc[3][1], 0,0,0);

#define LDA  a0 = lds_a[ab]; a1 = lds_a[ab+80]; a2 = lds_a[ab+160]; a3 = lds_a[ab+240]; ab -= 5;

__global__ __launch_bounds__(256) void conv_mfma(const __hip_bfloat16* __restrict__ GtB,
                                                 const __hip_bfloat16* __restrict__ xTB,
                                                 float* __restrict__ partial) {
    // LDS A window: 320 rows x 80 B (64 B data + 16 B pad -> uniform bank spread)
    __shared__ short8 lds_a[320*5];
    int tid  = threadIdx.x;
    int lane = tid & 63;
    int w    = tid >> 6;
    int jid  = blockIdx.x;
    int b    = jid / JOBS_PER_B;
    int r    = jid - b * JOBS_PER_B;
    int J = (int)((sqrtf(2.0f*r + 1.0f) - 1.0f) * 0.5f);
    while (2*(J+1)*(J+2) <= r) ++J;
    while (2*J*(J+1) > r) --J;
    int S  = r - 2*J*(J+1);
    int d0 = 64*S;

    const short8* xs = (const short8*)xTB;
    // window start row (global xT row index): covers t-d+PADR for t in [256J,256J+256), d in [d0,d0+64)
    int g0 = b*XT_ROWS + PADR + 256*J - 64*S - 63;
    #pragma unroll
    for (int c = 0; c < 5; ++c) {
        int lr = c*64 + (tid >> 2);
        lds_a[lr*5 + (tid & 3)] = xs[(size_t)(g0 + lr)*4 + (tid & 3)];
    }
    __syncthreads();

    int l15 = lane & 15, l4 = lane >> 4;
    const short8* gp = (const short8*)GtB + (size_t)d0*128 + l15*4 + l4;
    // A read base (short8 units): row(d) = 63 - (d-d0) + 64w + 16mt + l15, stride 5 units/row
    int ab = (63 + 64*w + l15)*5 + l4;

    f32x4 acc[4][2];
    const f32x4 zero = {0.f, 0.f, 0.f, 0.f};
    #pragma unroll
    for (int mt = 0; mt < 4; ++mt) { acc[mt][0] = zero; acc[mt][1] = zero; }

    short8 bx0 = gp[0], bx1 = gp[64]; gp += 128;   // B(d0)
    short8 by0, by1, a0, a1, a2, a3;

    for (int it = 0; it < 31; ++it) {
        by0 = gp[0]; by1 = gp[64]; gp += 128;      // B(d0+2it+1)
        LDA MFMA8(a0, a1, a2, a3, bx0, bx1)        // d = d0+2it
        bx0 = gp[0]; bx1 = gp[64]; gp += 128;      // B(d0+2it+2)
        LDA MFMA8(a0, a1, a2, a3, by0, by1)        // d = d0+2it+1
    }
    by0 = gp[0]; by1 = gp[64];                     // B(d0+63)
    LDA MFMA8(a0, a1, a2, a3, bx0, bx1)            // d = d0+62
    LDA MFMA8(a0, a1, a2, a3, by0, by1)            // d = d0+63

    // partial[jid][o][t_local], t_local in [0,256)
    float* pw = partial + (size_t)jid * 8192;
    #pragma unroll
    for (int no = 0; no < 2; ++no)
        #pragma unroll
        for (int mt = 0; mt < 4; ++mt) {
            int addr = (16*no + l15)*256 + 64*w + 16*mt + l4*4;
            *reinterpret_cast<f32x4*>(pw + addr) = acc[mt][no];
        }
}

// ---------------- K4: sum 4*(J+1) segments per (b,J) t-block, add bias ----------------
__global__ void reduce_out(const float* __restrict__ partial, const float* __restrict__ bias,
                           float* __restrict__ out) {
    int gid = blockIdx.x * 256 + threadIdx.x;      // 524288 elems
    int tl = gid & 255;
    int J  = (gid >> 8) & 7;
    int o  = (gid >> 11) & 31;
    int b  = gid >> 16;
    int jid = b*JOBS_PER_B + 2*J*(J+1);
    int cnt = 4*(J+1);                              // multiple of 4
    const float* p = partial + (size_t)jid*8192 + o*256 + tl;
    float s0 = 0.f, s1 = 0.f, s2 = 0.f, s3 = 0.f;
    for (int sg = 0; sg < cnt; sg += 4) {
        s0 += p[(size_t)sg*8192];
        s1 += p[(size_t)(sg+1)*8192];
        s2 += p[(size_t)(sg+2)*8192];
        s3 += p[(size_t)(sg+3)*8192];
    }
    out[((size_t)(b*32 + o))*TLEN + 256*J + tl] = bias[o] + ((s0 + s1) + (s2 + s3));
}

extern "C" void kernel_launch(void* const* d_in, const int* in_sizes, int n_in,
                              void* d_out, int out_size, void* d_ws, size_t ws_size,
                              hipStream_t stream) {
    const float* x    = (const float*)d_in[0];
    const float* pos  = (const float*)d_in[1];
    const float* w1   = (const float*)d_in[2];
    const float* b1   = (const float*)d_in[3];
    const float* w2   = (const float*)d_in[4];
    const float* b2   = (const float*)d_in[5];
    const float* w3   = (const float*)d_in[6];
    const float* b3   = (const float*)d_in[7];
    const float* bias = (const float*)d_in[8];
    float* out = (float*)d_out;

    char* ws = (char*)d_ws;
    __hip_bfloat16* Gt = (__hip_bfloat16*)ws;
    __hip_bfloat16* xT = (__hip_bfloat16*)(ws + GT_BYTES);
    float* partial     = (float*)(ws + PART_OFF);

    hipLaunchKernelGGL(gen_kernel,  dim3(256),   dim3(256), 0, stream,
                       pos, w1, b1, w2, b2, w3, b3, Gt);
    hipLaunchKernelGGL(transpose_x, dim3(256),   dim3(256), 0, stream, x, xT);
    hipLaunchKernelGGL(conv_mfma,   dim3(NJOBS), dim3(256), 0, stream, Gt, xT, partial);
    hipLaunchKernelGGL(reduce_out,  dim3(2048),  dim3(256), 0, stream, partial, bias, out);
}